// Round 6
// baseline (732.800 us; speedup 1.0000x reference)
//
#include <hip/hip_runtime.h>
#include <hip/hip_bf16.h>

#define N_NODES 50000
#define N_EDGES 800000
#define D 128
#define NBUCK 782   // 64 nodes per bucket
#define BCAP 2048   // mean 1024 edges/bucket; +32 sigma headroom

typedef __bf16 bf16;
typedef __attribute__((ext_vector_type(8))) __bf16 bf16x8;
typedef __attribute__((ext_vector_type(4))) __bf16 bf16x4;
typedef __attribute__((ext_vector_type(16))) float f32x16;
typedef _Float16 f16;
typedef __attribute__((ext_vector_type(2))) _Float16 f16x2;
typedef __attribute__((ext_vector_type(4))) _Float16 f16x4;
typedef __attribute__((ext_vector_type(8))) _Float16 f16x8;

// ---------------- init (zero accumulators) + W -> bf16 hi/lo fragment planes ---------
// blocks 0..63: prep; blocks 64..259: init.
__global__ __launch_bounds__(256)
void initprep_kernel(const float* __restrict__ W1, const float* __restrict__ W2,
                     bf16* __restrict__ WfH, bf16* __restrict__ WfL,
                     int* __restrict__ deg, int* __restrict__ bcnt,
                     float* __restrict__ stats, float* __restrict__ ppart,
                     float* __restrict__ pooled) {
    int b = blockIdx.x, t = threadIdx.x;
    if (b < 64) {
        // Frag layout (32x32x16 B-operand): col = lane&31, k = 8*(lane>>5)+j.
        int gid = b * 256 + t;    // 0..16383
        int lane = gid & 63;
        int grp = gid >> 6;       // 0..255
        int sub = grp & 7;
        int cf = (grp >> 3) & 3;
        int m = grp >> 5;         // 0..7
        const float* Wsrc = (m < 4) ? (W1 + m * 16384) : (W2 + (m - 4) * 16384);
        int col = cf * 32 + (lane & 31);
        int kb = sub * 16 + 8 * (lane >> 5);
        bf16x8 h, l;
#pragma unroll
        for (int j = 0; j < 8; ++j) {
            float w = Wsrc[(kb + j) * 128 + col];
            bf16 hb = (bf16)w;
            bf16 lb = (bf16)(w - (float)hb);
            h[j] = hb;
            l[j] = lb;
        }
        int idx = m * 16384 + ((grp & 31) * 64 + lane) * 8;
        *(bf16x8*)&WfH[idx] = h;
        *(bf16x8*)&WfL[idx] = l;
    } else {
        int i = (b - 64) * 256 + t;  // 0..50175
        if (i < N_NODES) deg[i] = 0;
        if (i < NBUCK) bcnt[i] = 0;
        if (i < 2048) stats[i] = 0.f;
        if (i < 24576) ppart[i] = 0.f;
        if (i < 640) pooled[i] = 0.f;
    }
}

// ---------------- degree histogram + bucket scatter (streaming writes) ----------------
__global__ void histbucket_kernel(const int* __restrict__ src, const int* __restrict__ dst,
                                  int* __restrict__ deg, int* __restrict__ bcnt,
                                  int2* __restrict__ bstore) {
    int e = blockIdx.x * 256 + threadIdx.x;
    int s = src[e], d = dst[e];
    atomicAdd(&deg[d], 1);
    int bk = d >> 6;
    int p = atomicAdd(&bcnt[bk], 1);
    if (p < BCAP) bstore[bk * BCAP + p] = make_int2(s, d);
}

// ---------------- parallel scan ----------------
__global__ __launch_bounds__(256)
void scanA_kernel(const int* __restrict__ deg, int* __restrict__ bsum) {
    __shared__ int red[256];
    int t = threadIdx.x;
    int g = blockIdx.x * 256 + t;
    red[t] = (g < N_NODES) ? deg[g] : 0;
    __syncthreads();
    for (int off = 128; off > 0; off >>= 1) {
        if (t < off) red[t] += red[t + off];
        __syncthreads();
    }
    if (t == 0) bsum[blockIdx.x] = red[0];
}

__global__ __launch_bounds__(256)
void scanB_kernel(const int* __restrict__ bsum, int* __restrict__ boff) {
    __shared__ int s[256];
    int t = threadIdx.x;
    s[t] = (t < 196) ? bsum[t] : 0;
    __syncthreads();
    for (int off = 1; off < 256; off <<= 1) {
        int a = (t >= off) ? s[t - off] : 0;
        __syncthreads();
        s[t] += a;
        __syncthreads();
    }
    boff[t] = (t == 0) ? 0 : s[t - 1];
}

__global__ __launch_bounds__(256)
void scanC_kernel(const int* __restrict__ deg, const int* __restrict__ boff,
                  int* __restrict__ row_start, int* __restrict__ cursor) {
    __shared__ int s[256];
    int t = threadIdx.x;
    int g = blockIdx.x * 256 + t;
    int v = (g < N_NODES) ? deg[g] : 0;
    s[t] = v;
    __syncthreads();
    for (int off = 1; off < 256; off <<= 1) {
        int a = (t >= off) ? s[t - off] : 0;
        __syncthreads();
        s[t] += a;
        __syncthreads();
    }
    int excl = boff[blockIdx.x] + s[t] - v;
    if (g < N_NODES) {
        row_start[g] = excl;
        cursor[g] = excl;
    }
    if (blockIdx.x == 0 && t == 0) row_start[N_NODES] = N_EDGES;
}

// ---------------- drain buckets -> exact CSC (LDS cursors, windowed esrc writes) ------
__global__ __launch_bounds__(256)
void fill2_kernel(const int* __restrict__ cursor, const int* __restrict__ bcnt,
                  const int2* __restrict__ bstore, int* __restrict__ esrc) {
    __shared__ int cur[64];
    int b = blockIdx.x;
    int t = threadIdx.x;
    int base = b << 6;
    if (t < 64) cur[t] = (base + t < N_NODES) ? cursor[base + t] : 0;
    __syncthreads();
    int n = min(bcnt[b], BCAP);
    for (int i = t; i < n; i += 256) {
        int2 sd = bstore[b * BCAP + i];
        int p = atomicAdd(&cur[sd.y - base], 1);
        esrc[p] = sd.x;
    }
}

// ---------------- conv0: Hb = (fp16) h0; pooled[0] += colsum h0 (fp32) ----------------
__global__ __launch_bounds__(256)
void conv0_kernel(const float* __restrict__ Y, f16* __restrict__ Hb,
                  float* __restrict__ pooled) {
    __shared__ float red[8][128];
    int t = threadIdx.x;
    int c = (t & 31) << 2;
    int rrow = t >> 5;
    float4 p = make_float4(0.f, 0.f, 0.f, 0.f);
    for (int r = blockIdx.x * 8 + rrow; r < N_NODES; r += gridDim.x * 8) {
        float4 v = *(const float4*)&Y[r * D + c];
        f16x4 h4;
        h4[0] = (f16)v.x; h4[1] = (f16)v.y; h4[2] = (f16)v.z; h4[3] = (f16)v.w;
        *(f16x4*)&Hb[r * D + c] = h4;
        p.x += v.x; p.y += v.y; p.z += v.z; p.w += v.w;
    }
    *(float4*)&red[rrow][c] = p;
    __syncthreads();
    if (t < 128) {
        float s = 0.f;
#pragma unroll
        for (int i = 0; i < 8; ++i) s += red[i][t];
        atomicAdd(&pooled[t], s);
    }
}

// ---------------- aggregation: z[v] = f(H[v]) + sum_{e->v} f(H[src]) ------------------
// H is raw fp16 (y2 of prev layer); f = relu(bn2) applied inline when APPLY.
// Self-term doubles as the per-layer pool contribution -> ppart (APPLY only).
template <bool APPLY>
__global__ __launch_bounds__(256)
void agg_kernel(const f16* __restrict__ H, const int* __restrict__ esrc,
                const int* __restrict__ row_start, const float* __restrict__ stats,
                const float* __restrict__ gam, const float* __restrict__ bet,
                f16* __restrict__ Z, float* __restrict__ ppart) {
    __shared__ float sred[4][128];
    int wv = threadIdx.x >> 6;
    int v = blockIdx.x * 4 + wv;
    int lane = threadIdx.x & 63;
    int c2 = lane << 1;
    float a0 = 1.f, b0 = 0.f, a1 = 1.f, b1 = 0.f;
    if (APPLY) {
        float m0 = stats[c2] * (1.0f / N_NODES);
        float q0 = stats[128 + c2] * (1.0f / N_NODES);
        float g0 = gam[c2] * rsqrtf(q0 - m0 * m0 + 1e-5f);
        a0 = g0; b0 = bet[c2] - m0 * g0;
        float m1 = stats[c2 + 1] * (1.0f / N_NODES);
        float q1 = stats[128 + c2 + 1] * (1.0f / N_NODES);
        float g1 = gam[c2 + 1] * rsqrtf(q1 - m1 * m1 + 1e-5f);
        a1 = g1; b1 = bet[c2 + 1] - m1 * g1;
    }
    int beg = row_start[v], end_ = row_start[v + 1];
    f16x2 sv = *(const f16x2*)&H[v * D + c2];
    float ax = (float)sv[0], ay = (float)sv[1];
    if (APPLY) {
        ax = fmaxf(fmaf(a0, ax, b0), 0.f);
        ay = fmaxf(fmaf(a1, ay, b1), 0.f);
        sred[wv][c2] = ax;
        sred[wv][c2 + 1] = ay;
    }
    int e = beg;
    for (; e + 4 <= end_; e += 4) {
        int s0 = esrc[e], s1 = esrc[e + 1], s2 = esrc[e + 2], s3 = esrc[e + 3];
        f16x2 v0 = *(const f16x2*)&H[s0 * D + c2];
        f16x2 v1 = *(const f16x2*)&H[s1 * D + c2];
        f16x2 v2 = *(const f16x2*)&H[s2 * D + c2];
        f16x2 v3 = *(const f16x2*)&H[s3 * D + c2];
        if (APPLY) {
            ax += fmaxf(fmaf(a0, (float)v0[0], b0), 0.f) + fmaxf(fmaf(a0, (float)v1[0], b0), 0.f)
                + fmaxf(fmaf(a0, (float)v2[0], b0), 0.f) + fmaxf(fmaf(a0, (float)v3[0], b0), 0.f);
            ay += fmaxf(fmaf(a1, (float)v0[1], b1), 0.f) + fmaxf(fmaf(a1, (float)v1[1], b1), 0.f)
                + fmaxf(fmaf(a1, (float)v2[1], b1), 0.f) + fmaxf(fmaf(a1, (float)v3[1], b1), 0.f);
        } else {
            ax += (float)v0[0] + (float)v1[0] + (float)v2[0] + (float)v3[0];
            ay += (float)v0[1] + (float)v1[1] + (float)v2[1] + (float)v3[1];
        }
    }
    for (; e < end_; ++e) {
        int s0 = esrc[e];
        f16x2 v0 = *(const f16x2*)&H[s0 * D + c2];
        if (APPLY) {
            ax += fmaxf(fmaf(a0, (float)v0[0], b0), 0.f);
            ay += fmaxf(fmaf(a1, (float)v0[1], b1), 0.f);
        } else {
            ax += (float)v0[0];
            ay += (float)v0[1];
        }
    }
    f16x2 zv;
    zv[0] = (f16)ax;
    zv[1] = (f16)ay;
    *(f16x2*)&Z[v * D + c2] = zv;
    if (APPLY) {
        __syncthreads();
        int t = threadIdx.x;
        if (t < 128) {
            float s = sred[0][t] + sred[1][t] + sred[2][t] + sred[3][t];
            atomicAdd(&ppart[(blockIdx.x & 63) * 128 + t], s);
        }
    }
}

// ---------------- matmul: Y(f16) = f(X f16) @ W via split-bf16 MFMA (3 passes) --------
// hi/lo bf16 split represents fp16 inputs exactly; lo*lo term dropped (~2^-16 rel).
template <bool BN_IN>
__global__ __launch_bounds__(256, 2)
void mm_kernel(const f16* __restrict__ X, const bf16* __restrict__ WfH,
               const bf16* __restrict__ WfL, const float* __restrict__ stats_in,
               const float* __restrict__ gam, const float* __restrict__ bet,
               f16* __restrict__ Y, float* __restrict__ stats_out) {
    __shared__ bf16 Ah[4096];  // [128 rows][32 k], XOR-swizzled
    __shared__ bf16 Al[4096];
    __shared__ float ab[2][128];

    int t = threadIdx.x;
    int w = t >> 6, lane = t & 63;
    if (BN_IN && t < 128) {
        float s = stats_in[t] * (1.0f / N_NODES);
        float q = stats_in[128 + t] * (1.0f / N_NODES);
        float a = gam[t] * rsqrtf(q - s * s + 1e-5f);
        ab[0][t] = a;
        ab[1][t] = bet[t] - s * a;
    }

    bf16x8 Bh[8], Bl[8];
#pragma unroll
    for (int c = 0; c < 8; ++c) {
        int idx = ((w * 8 + c) * 64 + lane) * 8;
        Bh[c] = *(const bf16x8*)&WfH[idx];
        Bl[c] = *(const bf16x8*)&WfL[idx];
    }

    f32x16 acc[4];
#pragma unroll
    for (int fr = 0; fr < 4; ++fr) acc[fr] = (f32x16)0.0f;

    int rowbase = blockIdx.x * 128;
    int nrows = min(128, N_NODES - rowbase);
    int srow = t >> 1;
    int sk0 = (t & 1) * 16;
    __syncthreads();  // ab ready

    for (int kb = 0; kb < 4; ++kb) {
        if (kb) __syncthreads();
        {
            float vf[16];
#pragma unroll
            for (int j = 0; j < 16; ++j) vf[j] = 0.f;
            if (srow < nrows) {
                const f16* xr = &X[(rowbase + srow) * D + kb * 32 + sk0];
                f16x8 u0 = *(const f16x8*)&xr[0];
                f16x8 u1 = *(const f16x8*)&xr[8];
#pragma unroll
                for (int j = 0; j < 8; ++j) {
                    vf[j] = (float)u0[j];
                    vf[8 + j] = (float)u1[j];
                }
                if (BN_IN) {
#pragma unroll
                    for (int j = 0; j < 16; ++j) {
                        int kg = kb * 32 + sk0 + j;
                        vf[j] = fmaxf(fmaf(ab[0][kg], vf[j], ab[1][kg]), 0.f);
                    }
                }
            }
#pragma unroll
            for (int i = 0; i < 4; ++i) {
                bf16x4 h4, l4;
#pragma unroll
                for (int j = 0; j < 4; ++j) {
                    bf16 hb = (bf16)vf[i * 4 + j];
                    h4[j] = hb;
                    l4[j] = (bf16)(vf[i * 4 + j] - (float)hb);
                }
                int e = srow * 32 + sk0 + i * 4;
                int es = e ^ ((srow & 7) << 3);
                *(bf16x4*)&Ah[es] = h4;
                *(bf16x4*)&Al[es] = l4;
            }
        }
        __syncthreads();
#pragma unroll
        for (int s2 = 0; s2 < 2; ++s2) {
            int sg = kb * 2 + s2;
#pragma unroll
            for (int fr = 0; fr < 4; ++fr) {
                int row = fr * 32 + (lane & 31);
                int e = row * 32 + s2 * 16 + 8 * (lane >> 5);
                int es = e ^ ((row & 7) << 3);
                bf16x8 ah = *(const bf16x8*)&Ah[es];
                bf16x8 al = *(const bf16x8*)&Al[es];
                acc[fr] = __builtin_amdgcn_mfma_f32_32x32x16_bf16(al, Bh[sg], acc[fr], 0, 0, 0);
                acc[fr] = __builtin_amdgcn_mfma_f32_32x32x16_bf16(ah, Bl[sg], acc[fr], 0, 0, 0);
                acc[fr] = __builtin_amdgcn_mfma_f32_32x32x16_bf16(ah, Bh[sg], acc[fr], 0, 0, 0);
            }
        }
    }

    // C/D frag: col = lane&31, row = (reg&3) + 8*(reg>>2) + 4*(lane>>5)
    int col = w * 32 + (lane & 31);
    float psum = 0.f, psq = 0.f;
#pragma unroll
    for (int fr = 0; fr < 4; ++fr) {
#pragma unroll
        for (int r = 0; r < 16; ++r) {
            float v = acc[fr][r];
            int row = fr * 32 + (r & 3) + 8 * (r >> 2) + 4 * (lane >> 5);
            if (row < nrows) Y[(rowbase + row) * D + col] = (f16)v;
            psum += v;
            psq += v * v;
        }
    }
    psum += __shfl_xor(psum, 32);
    psq += __shfl_xor(psq, 32);
    if (lane < 32) {
        atomicAdd(&stats_out[col], psum);
        atomicAdd(&stats_out[128 + col], psq);
    }
}

// ---------------- final pool: pooled[4] += colsum relu(bn2_3(Y f16)) ------------------
__global__ __launch_bounds__(256)
void pool4_kernel(const f16* __restrict__ Y, const float* __restrict__ stats,
                  const float* __restrict__ gam, const float* __restrict__ bet,
                  float* __restrict__ pooled) {
    __shared__ float abS[2][128];
    __shared__ float red[8][128];
    int t = threadIdx.x;
    if (t < 128) {
        float s = stats[t] * (1.0f / N_NODES);
        float q = stats[128 + t] * (1.0f / N_NODES);
        float a = gam[t] * rsqrtf(q - s * s + 1e-5f);
        abS[0][t] = a;
        abS[1][t] = bet[t] - s * a;
    }
    __syncthreads();
    int c = (t & 31) << 2;
    int rrow = t >> 5;
    float4 A = *(const float4*)&abS[0][c];
    float4 B = *(const float4*)&abS[1][c];
    float4 p = make_float4(0.f, 0.f, 0.f, 0.f);
    for (int r = blockIdx.x * 8 + rrow; r < N_NODES; r += gridDim.x * 8) {
        f16x4 v = *(const f16x4*)&Y[r * D + c];
        p.x += fmaxf(fmaf(A.x, (float)v[0], B.x), 0.f);
        p.y += fmaxf(fmaf(A.y, (float)v[1], B.y), 0.f);
        p.z += fmaxf(fmaf(A.z, (float)v[2], B.z), 0.f);
        p.w += fmaxf(fmaf(A.w, (float)v[3], B.w), 0.f);
    }
    *(float4*)&red[rrow][c] = p;
    __syncthreads();
    if (t < 128) {
        float s = 0.f;
#pragma unroll
        for (int i = 0; i < 8; ++i) s += red[i][t];
        atomicAdd(&pooled[t], s);
    }
}

// ---------------- heads: reduce ppart (layers 1..3) + apply prediction layers ---------
__global__ void head_kernel(const float* __restrict__ ppart, const float* __restrict__ pooled,
                            const float* __restrict__ pW, const float* __restrict__ pB,
                            float* __restrict__ out) {
    __shared__ float pl[5][128];
    int t = threadIdx.x;  // 128
    if (t < 128) {
        pl[0][t] = pooled[t];
        for (int l = 1; l <= 3; ++l) {
            float s = 0.f;
            for (int sl = 0; sl < 64; ++sl) s += ppart[(l - 1) * 8192 + sl * 128 + t];
            pl[l][t] = s;
        }
        pl[4][t] = pooled[512 + t];
    }
    __syncthreads();
    if (t < 64) {
        float acc = 0.f;
        for (int l = 0; l < 5; ++l) {
            acc += pB[l * 64 + t];
            const float* wp = pW + l * 8192;
            const float* p = pl[l];
            for (int c = 0; c < 128; ++c) acc += p[c] * wp[c * 64 + t];
        }
        out[t] = acc;
    }
}

extern "C" void kernel_launch(void* const* d_in, const int* in_sizes, int n_in,
                              void* d_out, int out_size, void* d_ws, size_t ws_size,
                              hipStream_t stream) {
    const float* h0 = (const float*)d_in[0];
    const int* src = (const int*)d_in[1];
    const int* dst = (const int*)d_in[2];
    const float* W1 = (const float*)d_in[3];
    const float* W2 = (const float*)d_in[4];
    const float* bn1_g = (const float*)d_in[5];
    const float* bn1_b = (const float*)d_in[6];
    const float* bn2_g = (const float*)d_in[7];
    const float* bn2_b = (const float*)d_in[8];
    const float* pW = (const float*)d_in[9];
    const float* pB = (const float*)d_in[10];
    float* out = (float*)d_out;

    char* ws = (char*)d_ws;
    f16* B0 = (f16*)(ws + 0);                   // h-carrier (hb0 / y2), 12.8 MB
    f16* B1 = (f16*)(ws + 12800000);            // z, 12.8 MB
    f16* B2 = (f16*)(ws + 25600000);            // y1, 12.8 MB
    int* esrc = (int*)(ws + 38400000);          // 3.2 MB
    int2* bstore = (int2*)(ws + 41600000);      // 782*2048*8 = 12.81 MB
    int* deg = (int*)(ws + 54412288);           // 200 KB
    int* row_start = (int*)(ws + 54612288);     // 200,004 B
    int* cursor = (int*)(ws + 54812304);        // 200 KB
    int* bcnt = (int*)(ws + 55012304);          // 3128 B
    int* bsum = (int*)(ws + 55015440);          // 784 B
    int* boff = (int*)(ws + 55016224);          // 1 KB
    float* stats = (float*)(ws + 55017248);     // 8 KB: [bn1 x4][bn2 x4] x 256 f
    float* ppart = (float*)(ws + 55025440);     // 3 layers x 64 x 128 = 96 KB
    float* pooled = (float*)(ws + 55123744);    // 5*128 f
    bf16* WfH = (bf16*)(ws + 55126304);         // 256 KB
    bf16* WfL = (bf16*)(ws + 55388448);         // 256 KB

    initprep_kernel<<<260, 256, 0, stream>>>(W1, W2, WfH, WfL, deg, bcnt, stats, ppart,
                                             pooled);
    histbucket_kernel<<<3125, 256, 0, stream>>>(src, dst, deg, bcnt, bstore);
    scanA_kernel<<<196, 256, 0, stream>>>(deg, bsum);
    scanB_kernel<<<1, 256, 0, stream>>>(bsum, boff);
    scanC_kernel<<<196, 256, 0, stream>>>(deg, boff, row_start, cursor);
    fill2_kernel<<<NBUCK, 256, 0, stream>>>(cursor, bcnt, bstore, esrc);
    conv0_kernel<<<512, 256, 0, stream>>>(h0, B0, pooled);

    for (int i = 0; i < 4; ++i) {
        if (i == 0) {
            agg_kernel<false><<<12500, 256, 0, stream>>>(B0, esrc, row_start, nullptr,
                                                         nullptr, nullptr, B1, nullptr);
        } else {
            agg_kernel<true><<<12500, 256, 0, stream>>>(
                B0, esrc, row_start, stats + (4 + i - 1) * 256, bn2_g + (i - 1) * 128,
                bn2_b + (i - 1) * 128, B1, ppart + (i - 1) * 8192);
        }
        mm_kernel<false><<<391, 256, 0, stream>>>(B1, WfH + i * 16384, WfL + i * 16384,
                                                  nullptr, nullptr, nullptr, B2,
                                                  stats + i * 256);
        mm_kernel<true><<<391, 256, 0, stream>>>(B2, WfH + (4 + i) * 16384,
                                                 WfL + (4 + i) * 16384, stats + i * 256,
                                                 bn1_g + i * 128, bn1_b + i * 128, B0,
                                                 stats + (4 + i) * 256);
    }
    pool4_kernel<<<512, 256, 0, stream>>>(B0, stats + 7 * 256, bn2_g + 3 * 128,
                                          bn2_b + 3 * 128, pooled + 512);
    head_kernel<<<1, 128, 0, stream>>>(ppart, pooled, pW, pB, out);
}

// Round 7
// 594.172 us; speedup vs baseline: 1.2333x; 1.2333x over previous
//
#include <hip/hip_runtime.h>
#include <hip/hip_bf16.h>

#define N_NODES 50000
#define N_EDGES 800000
#define D 128

typedef __bf16 bf16;
typedef __attribute__((ext_vector_type(8))) __bf16 bf16x8;
typedef __attribute__((ext_vector_type(4))) __bf16 bf16x4;
typedef __attribute__((ext_vector_type(16))) float f32x16;
typedef _Float16 f16;
typedef __attribute__((ext_vector_type(2))) _Float16 f16x2;
typedef __attribute__((ext_vector_type(4))) _Float16 f16x4;
typedef __attribute__((ext_vector_type(8))) _Float16 f16x8;

// ---------------- init (zero accumulators) + W -> bf16 hi/lo fragment planes ---------
// blocks 0..63: prep; blocks 64..259: init.
__global__ __launch_bounds__(256)
void initprep_kernel(const float* __restrict__ W1, const float* __restrict__ W2,
                     bf16* __restrict__ WfH, bf16* __restrict__ WfL,
                     int* __restrict__ deg, float* __restrict__ stats,
                     float* __restrict__ ppart, float* __restrict__ pooled,
                     int* __restrict__ done) {
    int b = blockIdx.x, t = threadIdx.x;
    if (b < 64) {
        // Frag layout (32x32x16 B-operand): col = lane&31, k = 8*(lane>>5)+j.
        int gid = b * 256 + t;    // 0..16383
        int lane = gid & 63;
        int grp = gid >> 6;       // 0..255
        int sub = grp & 7;
        int cf = (grp >> 3) & 3;
        int m = grp >> 5;         // 0..7
        const float* Wsrc = (m < 4) ? (W1 + m * 16384) : (W2 + (m - 4) * 16384);
        int col = cf * 32 + (lane & 31);
        int kb = sub * 16 + 8 * (lane >> 5);
        bf16x8 h, l;
#pragma unroll
        for (int j = 0; j < 8; ++j) {
            float w = Wsrc[(kb + j) * 128 + col];
            bf16 hb = (bf16)w;
            bf16 lb = (bf16)(w - (float)hb);
            h[j] = hb;
            l[j] = lb;
        }
        int idx = m * 16384 + ((grp & 31) * 64 + lane) * 8;
        *(bf16x8*)&WfH[idx] = h;
        *(bf16x8*)&WfL[idx] = l;
    } else {
        int i = (b - 64) * 256 + t;  // 0..50175
        if (i < N_NODES) deg[i] = 0;
        if (i < 2048) stats[i] = 0.f;
        if (i < 24576) ppart[i] = 0.f;
        if (i < 640) pooled[i] = 0.f;
        if (i < 2) done[i] = 0;
    }
}

// ---------------- degree histogram (50k counters -> low contention) ----------------
__global__ void hist_kernel(const int* __restrict__ dst, int* __restrict__ deg) {
    int e = blockIdx.x * 256 + threadIdx.x;
    atomicAdd(&deg[dst[e]], 1);
}

// ---------------- scan stage A+B merged (done-counter; agent-scope handoff) ----------
__global__ __launch_bounds__(256)
void scanAB_kernel(const int* __restrict__ deg, int* __restrict__ bsum,
                   int* __restrict__ boff, int* __restrict__ done) {
    __shared__ int red[256];
    __shared__ int lastflag;
    int t = threadIdx.x;
    int g = blockIdx.x * 256 + t;
    red[t] = (g < N_NODES) ? deg[g] : 0;
    __syncthreads();
    for (int off = 128; off > 0; off >>= 1) {
        if (t < off) red[t] += red[t + off];
        __syncthreads();
    }
    if (t == 0) {
        __hip_atomic_store(&bsum[blockIdx.x], red[0], __ATOMIC_RELEASE,
                           __HIP_MEMORY_SCOPE_AGENT);
        __threadfence();
        int v = atomicAdd(&done[0], 1);
        lastflag = (v == (int)gridDim.x - 1);
    }
    __syncthreads();
    if (!lastflag) return;
    // last block: scan the 196 block sums
    __shared__ int s[256];
    int v = (t < 196) ? __hip_atomic_load(&bsum[t], __ATOMIC_ACQUIRE,
                                          __HIP_MEMORY_SCOPE_AGENT)
                      : 0;
    s[t] = v;
    __syncthreads();
    for (int off = 1; off < 256; off <<= 1) {
        int a = (t >= off) ? s[t - off] : 0;
        __syncthreads();
        s[t] += a;
        __syncthreads();
    }
    boff[t] = (t == 0) ? 0 : s[t - 1];  // plain store; next kernel on stream sees it
}

// ---------------- stage C: per-element exclusive offsets ----------------
__global__ __launch_bounds__(256)
void scanC_kernel(const int* __restrict__ deg, const int* __restrict__ boff,
                  int* __restrict__ row_start, int* __restrict__ cursor) {
    __shared__ int s[256];
    int t = threadIdx.x;
    int g = blockIdx.x * 256 + t;
    int v = (g < N_NODES) ? deg[g] : 0;
    s[t] = v;
    __syncthreads();
    for (int off = 1; off < 256; off <<= 1) {
        int a = (t >= off) ? s[t - off] : 0;
        __syncthreads();
        s[t] += a;
        __syncthreads();
    }
    int excl = boff[blockIdx.x] + s[t] - v;
    if (g < N_NODES) {
        row_start[g] = excl;
        cursor[g] = excl;
    }
    if (blockIdx.x == 0 && t == 0) row_start[N_NODES] = N_EDGES;
}

// ---------------- fill CSC edge list (global cursors; contention-free) ----------------
__global__ void fill_kernel(const int* __restrict__ src, const int* __restrict__ dst,
                            int* __restrict__ cursor, int* __restrict__ esrc) {
    int e = blockIdx.x * 256 + threadIdx.x;
    int d = dst[e];
    int p = atomicAdd(&cursor[d], 1);
    esrc[p] = src[e];
}

// ---------------- conv0: Hb = (fp16) h0; pooled[0] += colsum h0 (fp32) ----------------
__global__ __launch_bounds__(256)
void conv0_kernel(const float* __restrict__ Y, f16* __restrict__ Hb,
                  float* __restrict__ pooled) {
    __shared__ float red[8][128];
    int t = threadIdx.x;
    int c = (t & 31) << 2;
    int rrow = t >> 5;
    float4 p = make_float4(0.f, 0.f, 0.f, 0.f);
    for (int r = blockIdx.x * 8 + rrow; r < N_NODES; r += gridDim.x * 8) {
        float4 v = *(const float4*)&Y[r * D + c];
        f16x4 h4;
        h4[0] = (f16)v.x; h4[1] = (f16)v.y; h4[2] = (f16)v.z; h4[3] = (f16)v.w;
        *(f16x4*)&Hb[r * D + c] = h4;
        p.x += v.x; p.y += v.y; p.z += v.z; p.w += v.w;
    }
    *(float4*)&red[rrow][c] = p;
    __syncthreads();
    if (t < 128) {
        float s = 0.f;
#pragma unroll
        for (int i = 0; i < 8; ++i) s += red[i][t];
        atomicAdd(&pooled[t], s);
    }
}

// ---------------- aggregation: z[v] = f(H[v]) + sum_{e->v} f(H[src]) ------------------
// H is raw fp16 (y2 of prev layer); f = relu(bn2) applied inline when APPLY.
// Self-term doubles as the per-layer pool contribution -> ppart (APPLY only).
template <bool APPLY>
__global__ __launch_bounds__(256)
void agg_kernel(const f16* __restrict__ H, const int* __restrict__ esrc,
                const int* __restrict__ row_start, const float* __restrict__ stats,
                const float* __restrict__ gam, const float* __restrict__ bet,
                f16* __restrict__ Z, float* __restrict__ ppart) {
    __shared__ float sred[4][128];
    int wv = threadIdx.x >> 6;
    int v = blockIdx.x * 4 + wv;
    int lane = threadIdx.x & 63;
    int c2 = lane << 1;
    float a0 = 1.f, b0 = 0.f, a1 = 1.f, b1 = 0.f;
    if (APPLY) {
        float m0 = stats[c2] * (1.0f / N_NODES);
        float q0 = stats[128 + c2] * (1.0f / N_NODES);
        float g0 = gam[c2] * rsqrtf(q0 - m0 * m0 + 1e-5f);
        a0 = g0; b0 = bet[c2] - m0 * g0;
        float m1 = stats[c2 + 1] * (1.0f / N_NODES);
        float q1 = stats[128 + c2 + 1] * (1.0f / N_NODES);
        float g1 = gam[c2 + 1] * rsqrtf(q1 - m1 * m1 + 1e-5f);
        a1 = g1; b1 = bet[c2 + 1] - m1 * g1;
    }
    int beg = row_start[v], end_ = row_start[v + 1];
    f16x2 sv = *(const f16x2*)&H[v * D + c2];
    float ax = (float)sv[0], ay = (float)sv[1];
    if (APPLY) {
        ax = fmaxf(fmaf(a0, ax, b0), 0.f);
        ay = fmaxf(fmaf(a1, ay, b1), 0.f);
        sred[wv][c2] = ax;
        sred[wv][c2 + 1] = ay;
    }
    int e = beg;
    for (; e + 4 <= end_; e += 4) {
        int s0 = esrc[e], s1 = esrc[e + 1], s2 = esrc[e + 2], s3 = esrc[e + 3];
        f16x2 v0 = *(const f16x2*)&H[s0 * D + c2];
        f16x2 v1 = *(const f16x2*)&H[s1 * D + c2];
        f16x2 v2 = *(const f16x2*)&H[s2 * D + c2];
        f16x2 v3 = *(const f16x2*)&H[s3 * D + c2];
        if (APPLY) {
            ax += fmaxf(fmaf(a0, (float)v0[0], b0), 0.f) + fmaxf(fmaf(a0, (float)v1[0], b0), 0.f)
                + fmaxf(fmaf(a0, (float)v2[0], b0), 0.f) + fmaxf(fmaf(a0, (float)v3[0], b0), 0.f);
            ay += fmaxf(fmaf(a1, (float)v0[1], b1), 0.f) + fmaxf(fmaf(a1, (float)v1[1], b1), 0.f)
                + fmaxf(fmaf(a1, (float)v2[1], b1), 0.f) + fmaxf(fmaf(a1, (float)v3[1], b1), 0.f);
        } else {
            ax += (float)v0[0] + (float)v1[0] + (float)v2[0] + (float)v3[0];
            ay += (float)v0[1] + (float)v1[1] + (float)v2[1] + (float)v3[1];
        }
    }
    for (; e < end_; ++e) {
        int s0 = esrc[e];
        f16x2 v0 = *(const f16x2*)&H[s0 * D + c2];
        if (APPLY) {
            ax += fmaxf(fmaf(a0, (float)v0[0], b0), 0.f);
            ay += fmaxf(fmaf(a1, (float)v0[1], b1), 0.f);
        } else {
            ax += (float)v0[0];
            ay += (float)v0[1];
        }
    }
    f16x2 zv;
    zv[0] = (f16)ax;
    zv[1] = (f16)ay;
    *(f16x2*)&Z[v * D + c2] = zv;
    if (APPLY) {
        __syncthreads();
        int t = threadIdx.x;
        if (t < 128) {
            float s = sred[0][t] + sred[1][t] + sred[2][t] + sred[3][t];
            atomicAdd(&ppart[(blockIdx.x & 63) * 128 + t], s);
        }
    }
}

// ---------------- matmul: Y(f16) = f(X f16) @ W via split-bf16 MFMA (3 passes) --------
// hi/lo bf16 split represents fp16 inputs exactly; lo*lo term dropped (~2^-16 rel).
template <bool BN_IN>
__global__ __launch_bounds__(256, 2)
void mm_kernel(const f16* __restrict__ X, const bf16* __restrict__ WfH,
               const bf16* __restrict__ WfL, const float* __restrict__ stats_in,
               const float* __restrict__ gam, const float* __restrict__ bet,
               f16* __restrict__ Y, float* __restrict__ stats_out) {
    __shared__ bf16 Ah[4096];  // [128 rows][32 k], XOR-swizzled
    __shared__ bf16 Al[4096];
    __shared__ float ab[2][128];

    int t = threadIdx.x;
    int w = t >> 6, lane = t & 63;
    if (BN_IN && t < 128) {
        float s = stats_in[t] * (1.0f / N_NODES);
        float q = stats_in[128 + t] * (1.0f / N_NODES);
        float a = gam[t] * rsqrtf(q - s * s + 1e-5f);
        ab[0][t] = a;
        ab[1][t] = bet[t] - s * a;
    }

    bf16x8 Bh[8], Bl[8];
#pragma unroll
    for (int c = 0; c < 8; ++c) {
        int idx = ((w * 8 + c) * 64 + lane) * 8;
        Bh[c] = *(const bf16x8*)&WfH[idx];
        Bl[c] = *(const bf16x8*)&WfL[idx];
    }

    f32x16 acc[4];
#pragma unroll
    for (int fr = 0; fr < 4; ++fr) acc[fr] = (f32x16)0.0f;

    int rowbase = blockIdx.x * 128;
    int nrows = min(128, N_NODES - rowbase);
    int srow = t >> 1;
    int sk0 = (t & 1) * 16;
    __syncthreads();  // ab ready

    for (int kb = 0; kb < 4; ++kb) {
        if (kb) __syncthreads();
        {
            float vf[16];
#pragma unroll
            for (int j = 0; j < 16; ++j) vf[j] = 0.f;
            if (srow < nrows) {
                const f16* xr = &X[(rowbase + srow) * D + kb * 32 + sk0];
                f16x8 u0 = *(const f16x8*)&xr[0];
                f16x8 u1 = *(const f16x8*)&xr[8];
#pragma unroll
                for (int j = 0; j < 8; ++j) {
                    vf[j] = (float)u0[j];
                    vf[8 + j] = (float)u1[j];
                }
                if (BN_IN) {
#pragma unroll
                    for (int j = 0; j < 16; ++j) {
                        int kg = kb * 32 + sk0 + j;
                        vf[j] = fmaxf(fmaf(ab[0][kg], vf[j], ab[1][kg]), 0.f);
                    }
                }
            }
#pragma unroll
            for (int i = 0; i < 4; ++i) {
                bf16x4 h4, l4;
#pragma unroll
                for (int j = 0; j < 4; ++j) {
                    bf16 hb = (bf16)vf[i * 4 + j];
                    h4[j] = hb;
                    l4[j] = (bf16)(vf[i * 4 + j] - (float)hb);
                }
                int e = srow * 32 + sk0 + i * 4;
                int es = e ^ ((srow & 7) << 3);
                *(bf16x4*)&Ah[es] = h4;
                *(bf16x4*)&Al[es] = l4;
            }
        }
        __syncthreads();
#pragma unroll
        for (int s2 = 0; s2 < 2; ++s2) {
            int sg = kb * 2 + s2;
#pragma unroll
            for (int fr = 0; fr < 4; ++fr) {
                int row = fr * 32 + (lane & 31);
                int e = row * 32 + s2 * 16 + 8 * (lane >> 5);
                int es = e ^ ((row & 7) << 3);
                bf16x8 ah = *(const bf16x8*)&Ah[es];
                bf16x8 al = *(const bf16x8*)&Al[es];
                acc[fr] = __builtin_amdgcn_mfma_f32_32x32x16_bf16(al, Bh[sg], acc[fr], 0, 0, 0);
                acc[fr] = __builtin_amdgcn_mfma_f32_32x32x16_bf16(ah, Bl[sg], acc[fr], 0, 0, 0);
                acc[fr] = __builtin_amdgcn_mfma_f32_32x32x16_bf16(ah, Bh[sg], acc[fr], 0, 0, 0);
            }
        }
    }

    // C/D frag: col = lane&31, row = (reg&3) + 8*(reg>>2) + 4*(lane>>5)
    int col = w * 32 + (lane & 31);
    float psum = 0.f, psq = 0.f;
#pragma unroll
    for (int fr = 0; fr < 4; ++fr) {
#pragma unroll
        for (int r = 0; r < 16; ++r) {
            float v = acc[fr][r];
            int row = fr * 32 + (r & 3) + 8 * (r >> 2) + 4 * (lane >> 5);
            if (row < nrows) Y[(rowbase + row) * D + col] = (f16)v;
            psum += v;
            psq += v * v;
        }
    }
    psum += __shfl_xor(psum, 32);
    psq += __shfl_xor(psq, 32);
    if (lane < 32) {
        atomicAdd(&stats_out[col], psum);
        atomicAdd(&stats_out[128 + col], psq);
    }
}

// ---------------- final pool + head (done-counter merge) ------------------------------
__global__ __launch_bounds__(256)
void pool4head_kernel(const f16* __restrict__ Y, const float* __restrict__ stats,
                      const float* __restrict__ gam, const float* __restrict__ bet,
                      float* __restrict__ pooled, const float* __restrict__ ppart,
                      const float* __restrict__ pW, const float* __restrict__ pB,
                      float* __restrict__ out, int* __restrict__ done) {
    __shared__ float abS[2][128];
    __shared__ float red[8][128];
    __shared__ int lastflag;
    int t = threadIdx.x;
    if (t < 128) {
        float s = stats[t] * (1.0f / N_NODES);
        float q = stats[128 + t] * (1.0f / N_NODES);
        float a = gam[t] * rsqrtf(q - s * s + 1e-5f);
        abS[0][t] = a;
        abS[1][t] = bet[t] - s * a;
    }
    __syncthreads();
    int c = (t & 31) << 2;
    int rrow = t >> 5;
    float4 A = *(const float4*)&abS[0][c];
    float4 B = *(const float4*)&abS[1][c];
    float4 p = make_float4(0.f, 0.f, 0.f, 0.f);
    for (int r = blockIdx.x * 8 + rrow; r < N_NODES; r += gridDim.x * 8) {
        f16x4 v = *(const f16x4*)&Y[r * D + c];
        p.x += fmaxf(fmaf(A.x, (float)v[0], B.x), 0.f);
        p.y += fmaxf(fmaf(A.y, (float)v[1], B.y), 0.f);
        p.z += fmaxf(fmaf(A.z, (float)v[2], B.z), 0.f);
        p.w += fmaxf(fmaf(A.w, (float)v[3], B.w), 0.f);
    }
    *(float4*)&red[rrow][c] = p;
    __syncthreads();
    if (t < 128) {
        float s = 0.f;
#pragma unroll
        for (int i = 0; i < 8; ++i) s += red[i][t];
        atomicAdd(&pooled[512 + t], s);
    }
    __syncthreads();
    if (t == 0) {
        __threadfence();
        int v = atomicAdd(&done[1], 1);
        lastflag = (v == (int)gridDim.x - 1);
    }
    __syncthreads();
    if (!lastflag) return;

    // last block: prediction heads
    __shared__ float pl[5][128];
    if (t < 128) {
        pl[0][t] = pooled[t];  // conv0 (previous kernel) - visible via stream order
        for (int l = 1; l <= 3; ++l) {
            float s = 0.f;
            for (int sl = 0; sl < 64; ++sl) s += ppart[(l - 1) * 8192 + sl * 128 + t];
            pl[l][t] = s;
        }
        // written by this launch's other blocks -> agent-scope atomic load
        pl[4][t] = __hip_atomic_load(&pooled[512 + t], __ATOMIC_ACQUIRE,
                                     __HIP_MEMORY_SCOPE_AGENT);
    }
    __syncthreads();
    if (t < 64) {
        float acc = 0.f;
        for (int l = 0; l < 5; ++l) {
            acc += pB[l * 64 + t];
            const float* wp = pW + l * 8192;
            const float* pp = pl[l];
            for (int cc = 0; cc < 128; ++cc) acc += pp[cc] * wp[cc * 64 + t];
        }
        out[t] = acc;
    }
}

extern "C" void kernel_launch(void* const* d_in, const int* in_sizes, int n_in,
                              void* d_out, int out_size, void* d_ws, size_t ws_size,
                              hipStream_t stream) {
    const float* h0 = (const float*)d_in[0];
    const int* src = (const int*)d_in[1];
    const int* dst = (const int*)d_in[2];
    const float* W1 = (const float*)d_in[3];
    const float* W2 = (const float*)d_in[4];
    const float* bn1_g = (const float*)d_in[5];
    const float* bn1_b = (const float*)d_in[6];
    const float* bn2_g = (const float*)d_in[7];
    const float* bn2_b = (const float*)d_in[8];
    const float* pW = (const float*)d_in[9];
    const float* pB = (const float*)d_in[10];
    float* out = (float*)d_out;

    char* ws = (char*)d_ws;
    f16* B0 = (f16*)(ws + 0);                   // h-carrier (hb0 / y2), 12.8 MB
    f16* B1 = (f16*)(ws + 12800000);            // z, 12.8 MB
    f16* B2 = (f16*)(ws + 25600000);            // y1, 12.8 MB
    int* esrc = (int*)(ws + 38400000);          // 3.2 MB
    int* deg = (int*)(ws + 54412288);           // 200 KB
    int* row_start = (int*)(ws + 54612288);     // 200,004 B
    int* cursor = (int*)(ws + 54812304);        // 200 KB
    int* done = (int*)(ws + 55012304);          // 8 B
    int* bsum = (int*)(ws + 55015440);          // 784 B
    int* boff = (int*)(ws + 55016224);          // 1 KB
    float* stats = (float*)(ws + 55017248);     // 8 KB: [bn1 x4][bn2 x4] x 256 f
    float* ppart = (float*)(ws + 55025440);     // 3 layers x 64 x 128 = 96 KB
    float* pooled = (float*)(ws + 55123744);    // 640 f
    bf16* WfH = (bf16*)(ws + 55126304);         // 256 KB
    bf16* WfL = (bf16*)(ws + 55388448);         // 256 KB

    initprep_kernel<<<260, 256, 0, stream>>>(W1, W2, WfH, WfL, deg, stats, ppart, pooled,
                                             done);
    hist_kernel<<<3125, 256, 0, stream>>>(dst, deg);
    scanAB_kernel<<<196, 256, 0, stream>>>(deg, bsum, boff, done);
    scanC_kernel<<<196, 256, 0, stream>>>(deg, boff, row_start, cursor);
    fill_kernel<<<3125, 256, 0, stream>>>(src, dst, cursor, esrc);
    conv0_kernel<<<512, 256, 0, stream>>>(h0, B0, pooled);

    for (int i = 0; i < 4; ++i) {
        if (i == 0) {
            agg_kernel<false><<<12500, 256, 0, stream>>>(B0, esrc, row_start, nullptr,
                                                         nullptr, nullptr, B1, nullptr);
        } else {
            agg_kernel<true><<<12500, 256, 0, stream>>>(
                B0, esrc, row_start, stats + (4 + i - 1) * 256, bn2_g + (i - 1) * 128,
                bn2_b + (i - 1) * 128, B1, ppart + (i - 1) * 8192);
        }
        mm_kernel<false><<<391, 256, 0, stream>>>(B1, WfH + i * 16384, WfL + i * 16384,
                                                  nullptr, nullptr, nullptr, B2,
                                                  stats + i * 256);
        mm_kernel<true><<<391, 256, 0, stream>>>(B2, WfH + (4 + i) * 16384,
                                                 WfL + (4 + i) * 16384, stats + i * 256,
                                                 bn1_g + i * 128, bn1_b + i * 128, B0,
                                                 stats + (4 + i) * 256);
    }
    pool4head_kernel<<<512, 256, 0, stream>>>(B0, stats + 7 * 256, bn2_g + 3 * 128,
                                              bn2_b + 3 * 128, pooled, ppart, pW, pB, out,
                                              done);
}

// Round 8
// 542.758 us; speedup vs baseline: 1.3501x; 1.0947x over previous
//
#include <hip/hip_runtime.h>
#include <hip/hip_bf16.h>

#define N_NODES 50000
#define N_EDGES 800000
#define D 128

typedef __bf16 bf16;
typedef __attribute__((ext_vector_type(8))) __bf16 bf16x8;
typedef __attribute__((ext_vector_type(4))) __bf16 bf16x4;
typedef __attribute__((ext_vector_type(16))) float f32x16;
typedef _Float16 f16;
typedef __attribute__((ext_vector_type(2))) _Float16 f16x2;
typedef __attribute__((ext_vector_type(4))) _Float16 f16x4;
typedef __attribute__((ext_vector_type(8))) _Float16 f16x8;

// ---------------- initprep: W->bf16 hi/lo planes | zero accumulators | conv0 ----------
// blocks 0..63: prep; 64..259: init zeros; 260..771: Hb = fp16(h0).
__global__ __launch_bounds__(256)
void initprep_kernel(const float* __restrict__ W1, const float* __restrict__ W2,
                     bf16* __restrict__ WfH, bf16* __restrict__ WfL,
                     int* __restrict__ deg, float* __restrict__ stats,
                     float* __restrict__ ppart, float* __restrict__ plglob,
                     float* __restrict__ pooled4, int* __restrict__ done,
                     int* __restrict__ flags, const float* __restrict__ h0,
                     f16* __restrict__ Hb) {
    int b = blockIdx.x, t = threadIdx.x;
    if (b < 64) {
        // Frag layout (32x32x16 B-operand): col = lane&31, k = 8*(lane>>5)+j.
        int gid = b * 256 + t;    // 0..16383
        int lane = gid & 63;
        int grp = gid >> 6;       // 0..255
        int sub = grp & 7;
        int cf = (grp >> 3) & 3;
        int m = grp >> 5;         // 0..7
        const float* Wsrc = (m < 4) ? (W1 + m * 16384) : (W2 + (m - 4) * 16384);
        int col = cf * 32 + (lane & 31);
        int kb = sub * 16 + 8 * (lane >> 5);
        bf16x8 h, l;
#pragma unroll
        for (int j = 0; j < 8; ++j) {
            float w = Wsrc[(kb + j) * 128 + col];
            bf16 hb = (bf16)w;
            bf16 lb = (bf16)(w - (float)hb);
            h[j] = hb;
            l[j] = lb;
        }
        int idx = m * 16384 + ((grp & 31) * 64 + lane) * 8;
        *(bf16x8*)&WfH[idx] = h;
        *(bf16x8*)&WfL[idx] = l;
    } else if (b < 260) {
        int i = (b - 64) * 256 + t;  // 0..50175
        if (i < N_NODES) deg[i] = 0;
        if (i < 2048) stats[i] = 0.f;
        if (i < 32768) ppart[i] = 0.f;
        if (i < 512) plglob[i] = 0.f;
        if (i < 128) pooled4[i] = 0.f;
        if (i < 2) done[i] = 0;
        if (i < 196) flags[i] = 0;
    } else {
        // conv0: fp16-round h0 (pool of hidden_rep[0] happens in agg's self-term)
        int c = (t & 31) << 2;
        int rrow = t >> 5;
        for (int r = (b - 260) * 8 + rrow; r < N_NODES; r += 512 * 8) {
            float4 v = *(const float4*)&h0[r * D + c];
            f16x4 h4;
            h4[0] = (f16)v.x; h4[1] = (f16)v.y; h4[2] = (f16)v.z; h4[3] = (f16)v.w;
            *(f16x4*)&Hb[r * D + c] = h4;
        }
    }
}

// ---------------- degree histogram (50k counters -> low contention) ----------------
__global__ void hist_kernel(const int* __restrict__ dst, int* __restrict__ deg) {
    int e = blockIdx.x * 256 + threadIdx.x;
    atomicAdd(&deg[dst[e]], 1);
}

// ---------------- single-kernel scan (decoupled lookback; 196 co-resident blocks) -----
__global__ __launch_bounds__(256)
void scan_kernel(const int* __restrict__ deg, int* __restrict__ bsum,
                 int* __restrict__ flags, int* __restrict__ row_start,
                 int* __restrict__ cursor) {
    __shared__ int s[256];
    __shared__ int rsum[256];
    int t = threadIdx.x, b = blockIdx.x;
    int g = b * 256 + t;
    int v = (g < N_NODES) ? deg[g] : 0;
    s[t] = v;
    __syncthreads();
    for (int off = 1; off < 256; off <<= 1) {
        int a = (t >= off) ? s[t - off] : 0;
        __syncthreads();
        s[t] += a;
        __syncthreads();
    }
    if (t == 0) {
        __hip_atomic_store(&bsum[b], s[255], __ATOMIC_RELEASE, __HIP_MEMORY_SCOPE_AGENT);
        __hip_atomic_store(&flags[b], 1, __ATOMIC_RELEASE, __HIP_MEMORY_SCOPE_AGENT);
    }
    // sum of previous blocks' totals (all blocks resident -> spin is safe)
    int part = 0;
    for (int j = t; j < b; j += 256) {
        while (__hip_atomic_load(&flags[j], __ATOMIC_ACQUIRE, __HIP_MEMORY_SCOPE_AGENT) == 0) {}
        part += __hip_atomic_load(&bsum[j], __ATOMIC_ACQUIRE, __HIP_MEMORY_SCOPE_AGENT);
    }
    rsum[t] = part;
    __syncthreads();
    for (int off = 128; off > 0; off >>= 1) {
        if (t < off) rsum[t] += rsum[t + off];
        __syncthreads();
    }
    int excl = rsum[0] + s[t] - v;
    if (g < N_NODES) {
        row_start[g] = excl;
        cursor[g] = excl;
    }
    if (b == 0 && t == 0) row_start[N_NODES] = N_EDGES;
}

// ---------------- fill CSC edge list (global cursors; contention-free) ----------------
__global__ void fill_kernel(const int* __restrict__ src, const int* __restrict__ dst,
                            int* __restrict__ cursor, int* __restrict__ esrc) {
    int e = blockIdx.x * 256 + threadIdx.x;
    int d = dst[e];
    int p = atomicAdd(&cursor[d], 1);
    esrc[p] = src[e];
}

// ---------------- aggregation: z[v] = f(H[v]) + sum_{e->v} f(H[src]) ------------------
// H is raw fp16 (h0 or y2 of prev layer); f = relu(bn2) when APPLY, identity otherwise.
// Self-term f(H[v]) is the pool contribution of hidden_rep[layer] -> ppart.
template <bool APPLY>
__global__ __launch_bounds__(256)
void agg_kernel(const f16* __restrict__ H, const int* __restrict__ esrc,
                const int* __restrict__ row_start, const float* __restrict__ stats,
                const float* __restrict__ gam, const float* __restrict__ bet,
                f16* __restrict__ Z, float* __restrict__ ppart) {
    __shared__ float sred[4][128];
    int wv = threadIdx.x >> 6;
    int v = blockIdx.x * 4 + wv;
    int lane = threadIdx.x & 63;
    int c2 = lane << 1;
    float a0 = 1.f, b0 = 0.f, a1 = 1.f, b1 = 0.f;
    if (APPLY) {
        float m0 = stats[c2] * (1.0f / N_NODES);
        float q0 = stats[128 + c2] * (1.0f / N_NODES);
        float g0 = gam[c2] * rsqrtf(q0 - m0 * m0 + 1e-5f);
        a0 = g0; b0 = bet[c2] - m0 * g0;
        float m1 = stats[c2 + 1] * (1.0f / N_NODES);
        float q1 = stats[128 + c2 + 1] * (1.0f / N_NODES);
        float g1 = gam[c2 + 1] * rsqrtf(q1 - m1 * m1 + 1e-5f);
        a1 = g1; b1 = bet[c2 + 1] - m1 * g1;
    }
    int beg = row_start[v], end_ = row_start[v + 1];
    f16x2 sv = *(const f16x2*)&H[v * D + c2];
    float ax = (float)sv[0], ay = (float)sv[1];
    if (APPLY) {
        ax = fmaxf(fmaf(a0, ax, b0), 0.f);
        ay = fmaxf(fmaf(a1, ay, b1), 0.f);
    }
    sred[wv][c2] = ax;
    sred[wv][c2 + 1] = ay;
    int e = beg;
    for (; e + 4 <= end_; e += 4) {
        int s0 = esrc[e], s1 = esrc[e + 1], s2 = esrc[e + 2], s3 = esrc[e + 3];
        f16x2 v0 = *(const f16x2*)&H[s0 * D + c2];
        f16x2 v1 = *(const f16x2*)&H[s1 * D + c2];
        f16x2 v2 = *(const f16x2*)&H[s2 * D + c2];
        f16x2 v3 = *(const f16x2*)&H[s3 * D + c2];
        if (APPLY) {
            ax += fmaxf(fmaf(a0, (float)v0[0], b0), 0.f) + fmaxf(fmaf(a0, (float)v1[0], b0), 0.f)
                + fmaxf(fmaf(a0, (float)v2[0], b0), 0.f) + fmaxf(fmaf(a0, (float)v3[0], b0), 0.f);
            ay += fmaxf(fmaf(a1, (float)v0[1], b1), 0.f) + fmaxf(fmaf(a1, (float)v1[1], b1), 0.f)
                + fmaxf(fmaf(a1, (float)v2[1], b1), 0.f) + fmaxf(fmaf(a1, (float)v3[1], b1), 0.f);
        } else {
            ax += (float)v0[0] + (float)v1[0] + (float)v2[0] + (float)v3[0];
            ay += (float)v0[1] + (float)v1[1] + (float)v2[1] + (float)v3[1];
        }
    }
    for (; e < end_; ++e) {
        int s0 = esrc[e];
        f16x2 v0 = *(const f16x2*)&H[s0 * D + c2];
        if (APPLY) {
            ax += fmaxf(fmaf(a0, (float)v0[0], b0), 0.f);
            ay += fmaxf(fmaf(a1, (float)v0[1], b1), 0.f);
        } else {
            ax += (float)v0[0];
            ay += (float)v0[1];
        }
    }
    f16x2 zv;
    zv[0] = (f16)ax;
    zv[1] = (f16)ay;
    *(f16x2*)&Z[v * D + c2] = zv;
    __syncthreads();
    int t = threadIdx.x;
    if (t < 128) {
        float s = sred[0][t] + sred[1][t] + sred[2][t] + sred[3][t];
        atomicAdd(&ppart[(blockIdx.x & 63) * 128 + t], s);
    }
}

// ---------------- matmul: Y(f16) = f(X f16) @ W via split-bf16 MFMA (3 passes) --------
// hi/lo bf16 split represents fp16 inputs exactly; lo*lo term dropped (~2^-16 rel).
template <bool BN_IN>
__global__ __launch_bounds__(256, 2)
void mm_kernel(const f16* __restrict__ X, const bf16* __restrict__ WfH,
               const bf16* __restrict__ WfL, const float* __restrict__ stats_in,
               const float* __restrict__ gam, const float* __restrict__ bet,
               f16* __restrict__ Y, float* __restrict__ stats_out) {
    __shared__ bf16 Ah[4096];  // [128 rows][32 k], XOR-swizzled
    __shared__ bf16 Al[4096];
    __shared__ float ab[2][128];

    int t = threadIdx.x;
    int w = t >> 6, lane = t & 63;
    if (BN_IN && t < 128) {
        float s = stats_in[t] * (1.0f / N_NODES);
        float q = stats_in[128 + t] * (1.0f / N_NODES);
        float a = gam[t] * rsqrtf(q - s * s + 1e-5f);
        ab[0][t] = a;
        ab[1][t] = bet[t] - s * a;
    }

    bf16x8 Bh[8], Bl[8];
#pragma unroll
    for (int c = 0; c < 8; ++c) {
        int idx = ((w * 8 + c) * 64 + lane) * 8;
        Bh[c] = *(const bf16x8*)&WfH[idx];
        Bl[c] = *(const bf16x8*)&WfL[idx];
    }

    f32x16 acc[4];
#pragma unroll
    for (int fr = 0; fr < 4; ++fr) acc[fr] = (f32x16)0.0f;

    int rowbase = blockIdx.x * 128;
    int nrows = min(128, N_NODES - rowbase);
    int srow = t >> 1;
    int sk0 = (t & 1) * 16;
    __syncthreads();  // ab ready

    for (int kb = 0; kb < 4; ++kb) {
        if (kb) __syncthreads();
        {
            float vf[16];
#pragma unroll
            for (int j = 0; j < 16; ++j) vf[j] = 0.f;
            if (srow < nrows) {
                const f16* xr = &X[(rowbase + srow) * D + kb * 32 + sk0];
                f16x8 u0 = *(const f16x8*)&xr[0];
                f16x8 u1 = *(const f16x8*)&xr[8];
#pragma unroll
                for (int j = 0; j < 8; ++j) {
                    vf[j] = (float)u0[j];
                    vf[8 + j] = (float)u1[j];
                }
                if (BN_IN) {
#pragma unroll
                    for (int j = 0; j < 16; ++j) {
                        int kg = kb * 32 + sk0 + j;
                        vf[j] = fmaxf(fmaf(ab[0][kg], vf[j], ab[1][kg]), 0.f);
                    }
                }
            }
#pragma unroll
            for (int i = 0; i < 4; ++i) {
                bf16x4 h4, l4;
#pragma unroll
                for (int j = 0; j < 4; ++j) {
                    bf16 hb = (bf16)vf[i * 4 + j];
                    h4[j] = hb;
                    l4[j] = (bf16)(vf[i * 4 + j] - (float)hb);
                }
                int e = srow * 32 + sk0 + i * 4;
                int es = e ^ ((srow & 7) << 3);
                *(bf16x4*)&Ah[es] = h4;
                *(bf16x4*)&Al[es] = l4;
            }
        }
        __syncthreads();
#pragma unroll
        for (int s2 = 0; s2 < 2; ++s2) {
            int sg = kb * 2 + s2;
#pragma unroll
            for (int fr = 0; fr < 4; ++fr) {
                int row = fr * 32 + (lane & 31);
                int e = row * 32 + s2 * 16 + 8 * (lane >> 5);
                int es = e ^ ((row & 7) << 3);
                bf16x8 ah = *(const bf16x8*)&Ah[es];
                bf16x8 al = *(const bf16x8*)&Al[es];
                acc[fr] = __builtin_amdgcn_mfma_f32_32x32x16_bf16(al, Bh[sg], acc[fr], 0, 0, 0);
                acc[fr] = __builtin_amdgcn_mfma_f32_32x32x16_bf16(ah, Bl[sg], acc[fr], 0, 0, 0);
                acc[fr] = __builtin_amdgcn_mfma_f32_32x32x16_bf16(ah, Bh[sg], acc[fr], 0, 0, 0);
            }
        }
    }

    // C/D frag: col = lane&31, row = (reg&3) + 8*(reg>>2) + 4*(lane>>5)
    int col = w * 32 + (lane & 31);
    float psum = 0.f, psq = 0.f;
#pragma unroll
    for (int fr = 0; fr < 4; ++fr) {
#pragma unroll
        for (int r = 0; r < 16; ++r) {
            float v = acc[fr][r];
            int row = fr * 32 + (r & 3) + 8 * (r >> 2) + 4 * (lane >> 5);
            if (row < nrows) Y[(rowbase + row) * D + col] = (f16)v;
            psum += v;
            psq += v * v;
        }
    }
    psum += __shfl_xor(psum, 32);
    psq += __shfl_xor(psq, 32);
    if (lane < 32) {
        atomicAdd(&stats_out[col], psum);
        atomicAdd(&stats_out[128 + col], psq);
    }
}

// ---------------- final pool + parallel head (done-counter merge) ---------------------
__global__ __launch_bounds__(256)
void pool4head_kernel(const f16* __restrict__ Y, const float* __restrict__ stats,
                      const float* __restrict__ gam, const float* __restrict__ bet,
                      const float* __restrict__ ppart, float* __restrict__ plglob,
                      float* __restrict__ pooled4, const float* __restrict__ pW,
                      const float* __restrict__ pB, float* __restrict__ out,
                      int* __restrict__ done) {
    __shared__ float abS[2][128];
    __shared__ float red[8][128];
    __shared__ int lastflag;
    int t = threadIdx.x, b = blockIdx.x;

    // blocks 0..3: reduce ppart layer b -> plglob (pipelined, coalesced)
    if (b < 4 && t < 128) {
        float s = 0.f;
#pragma unroll
        for (int sl = 0; sl < 64; ++sl) s += ppart[b * 8192 + sl * 128 + t];
        __hip_atomic_store(&plglob[b * 128 + t], s, __ATOMIC_RELEASE,
                           __HIP_MEMORY_SCOPE_AGENT);
    }

    // all blocks: pool of relu(bn2_3(Y))
    if (t < 128) {
        float s = stats[t] * (1.0f / N_NODES);
        float q = stats[128 + t] * (1.0f / N_NODES);
        float a = gam[t] * rsqrtf(q - s * s + 1e-5f);
        abS[0][t] = a;
        abS[1][t] = bet[t] - s * a;
    }
    __syncthreads();
    int c = (t & 31) << 2;
    int rrow = t >> 5;
    float4 A = *(const float4*)&abS[0][c];
    float4 B = *(const float4*)&abS[1][c];
    float4 p = make_float4(0.f, 0.f, 0.f, 0.f);
    for (int r = b * 8 + rrow; r < N_NODES; r += gridDim.x * 8) {
        f16x4 v = *(const f16x4*)&Y[r * D + c];
        p.x += fmaxf(fmaf(A.x, (float)v[0], B.x), 0.f);
        p.y += fmaxf(fmaf(A.y, (float)v[1], B.y), 0.f);
        p.z += fmaxf(fmaf(A.z, (float)v[2], B.z), 0.f);
        p.w += fmaxf(fmaf(A.w, (float)v[3], B.w), 0.f);
    }
    *(float4*)&red[rrow][c] = p;
    __syncthreads();
    if (t < 128) {
        float s = 0.f;
#pragma unroll
        for (int i = 0; i < 8; ++i) s += red[i][t];
        atomicAdd(&pooled4[t], s);
    }
    __syncthreads();  // implies vmcnt(0): this block's atomics are complete
    if (t == 0) {
        __threadfence();
        int v = atomicAdd(&done[1], 1);
        lastflag = (v == (int)gridDim.x - 1);
    }
    __syncthreads();
    if (!lastflag) return;

    // last block: parallel head GEMV (o = t&63, 4-way K split, 2 accumulators)
    __shared__ float pl[5][128];
    __shared__ float red2[4][64];
    if (t < 128) {
#pragma unroll
        for (int l = 0; l < 4; ++l)
            pl[l][t] = __hip_atomic_load(&plglob[l * 128 + t], __ATOMIC_ACQUIRE,
                                         __HIP_MEMORY_SCOPE_AGENT);
        pl[4][t] = __hip_atomic_load(&pooled4[t], __ATOMIC_ACQUIRE,
                                     __HIP_MEMORY_SCOPE_AGENT);
    }
    __syncthreads();
    int o = t & 63, q = t >> 6;
    float acc0 = 0.f, acc1 = 0.f;
#pragma unroll
    for (int l = 0; l < 5; ++l) {
        const float* wp = pW + l * 8192;
#pragma unroll
        for (int cc = 0; cc < 16; ++cc) {
            int c0 = q * 32 + cc;
            int c1 = q * 32 + 16 + cc;
            acc0 += pl[l][c0] * wp[c0 * 64 + o];
            acc1 += pl[l][c1] * wp[c1 * 64 + o];
        }
    }
    red2[q][o] = acc0 + acc1;
    __syncthreads();
    if (t < 64) {
        float s = red2[0][t] + red2[1][t] + red2[2][t] + red2[3][t];
#pragma unroll
        for (int l = 0; l < 5; ++l) s += pB[l * 64 + t];
        out[t] = s;
    }
}

extern "C" void kernel_launch(void* const* d_in, const int* in_sizes, int n_in,
                              void* d_out, int out_size, void* d_ws, size_t ws_size,
                              hipStream_t stream) {
    const float* h0 = (const float*)d_in[0];
    const int* src = (const int*)d_in[1];
    const int* dst = (const int*)d_in[2];
    const float* W1 = (const float*)d_in[3];
    const float* W2 = (const float*)d_in[4];
    const float* bn1_g = (const float*)d_in[5];
    const float* bn1_b = (const float*)d_in[6];
    const float* bn2_g = (const float*)d_in[7];
    const float* bn2_b = (const float*)d_in[8];
    const float* pW = (const float*)d_in[9];
    const float* pB = (const float*)d_in[10];
    float* out = (float*)d_out;

    char* ws = (char*)d_ws;
    f16* B0 = (f16*)(ws + 0);                   // h-carrier (hb0 / y2), 12.8 MB
    f16* B1 = (f16*)(ws + 12800000);            // z, 12.8 MB
    f16* B2 = (f16*)(ws + 25600000);            // y1, 12.8 MB
    int* esrc = (int*)(ws + 38400000);          // 3.2 MB
    int* deg = (int*)(ws + 41600000);           // 200 KB
    int* row_start = (int*)(ws + 41800000);     // 200,004 B
    int* cursor = (int*)(ws + 42000016);        // 200 KB
    int* bsum = (int*)(ws + 42200016);          // 784 B
    int* flags = (int*)(ws + 42200800);         // 784 B
    int* done = (int*)(ws + 42201600);          // 8 B
    float* stats = (float*)(ws + 42201664);     // 8 KB: [bn1 x4][bn2 x4] x 256 f
    float* ppart = (float*)(ws + 42209856);     // 4 layers x 64 x 128 = 128 KB
    float* plglob = (float*)(ws + 42340928);    // 4 x 128 f
    float* pooled4 = (float*)(ws + 42342976);   // 128 f
    bf16* WfH = (bf16*)(ws + 42343488);         // 256 KB
    bf16* WfL = (bf16*)(ws + 42605632);         // 256 KB

    initprep_kernel<<<772, 256, 0, stream>>>(W1, W2, WfH, WfL, deg, stats, ppart, plglob,
                                             pooled4, done, flags, h0, B0);
    hist_kernel<<<3125, 256, 0, stream>>>(dst, deg);
    scan_kernel<<<196, 256, 0, stream>>>(deg, bsum, flags, row_start, cursor);
    fill_kernel<<<3125, 256, 0, stream>>>(src, dst, cursor, esrc);

    for (int i = 0; i < 4; ++i) {
        if (i == 0) {
            agg_kernel<false><<<12500, 256, 0, stream>>>(B0, esrc, row_start, nullptr,
                                                         nullptr, nullptr, B1, ppart);
        } else {
            agg_kernel<true><<<12500, 256, 0, stream>>>(
                B0, esrc, row_start, stats + (4 + i - 1) * 256, bn2_g + (i - 1) * 128,
                bn2_b + (i - 1) * 128, B1, ppart + i * 8192);
        }
        mm_kernel<false><<<391, 256, 0, stream>>>(B1, WfH + i * 16384, WfL + i * 16384,
                                                  nullptr, nullptr, nullptr, B2,
                                                  stats + i * 256);
        mm_kernel<true><<<391, 256, 0, stream>>>(B2, WfH + (4 + i) * 16384,
                                                 WfL + (4 + i) * 16384, stats + i * 256,
                                                 bn1_g + i * 128, bn1_b + i * 128, B0,
                                                 stats + (4 + i) * 256);
    }
    pool4head_kernel<<<512, 256, 0, stream>>>(B0, stats + 7 * 256, bn2_g + 3 * 128,
                                              bn2_b + 3 * 128, ppart, plglob, pooled4, pW,
                                              pB, out, done);
}

// Round 10
// 475.833 us; speedup vs baseline: 1.5400x; 1.1406x over previous
//
#include <hip/hip_runtime.h>
#include <hip/hip_bf16.h>

#define N_NODES 50000
#define N_EDGES 800000
#define D 128
#define NBUCK 98      // dst>>9 -> 512 nodes per bucket
#define BCAP 16384    // mean 8163, sigma ~90 -> 91-sigma headroom

typedef __bf16 bf16;
typedef __attribute__((ext_vector_type(8))) __bf16 bf16x8;
typedef __attribute__((ext_vector_type(4))) __bf16 bf16x4;
typedef __attribute__((ext_vector_type(16))) float f32x16;
typedef _Float16 f16;
typedef __attribute__((ext_vector_type(2))) _Float16 f16x2;
typedef __attribute__((ext_vector_type(4))) _Float16 f16x4;
typedef __attribute__((ext_vector_type(8))) _Float16 f16x8;

// ---------------- initprep: W->bf16 hi/lo planes | zero accumulators | conv0 ----------
// blocks 0..63: prep; 64..259: init zeros; 260..771: Hb = fp16(h0).
__global__ __launch_bounds__(256)
void initprep_kernel(const float* __restrict__ W1, const float* __restrict__ W2,
                     bf16* __restrict__ WfH, bf16* __restrict__ WfL,
                     int* __restrict__ bucketCnt, float* __restrict__ stats,
                     float* __restrict__ ppart, float* __restrict__ plglob,
                     float* __restrict__ pooled4, int* __restrict__ done,
                     const float* __restrict__ h0, f16* __restrict__ Hb) {
    int b = blockIdx.x, t = threadIdx.x;
    if (b < 64) {
        // Frag layout (32x32x16 B-operand): col = lane&31, k = 8*(lane>>5)+j.
        int gid = b * 256 + t;    // 0..16383
        int lane = gid & 63;
        int grp = gid >> 6;       // 0..255
        int sub = grp & 7;
        int cf = (grp >> 3) & 3;
        int m = grp >> 5;         // 0..7
        const float* Wsrc = (m < 4) ? (W1 + m * 16384) : (W2 + (m - 4) * 16384);
        int col = cf * 32 + (lane & 31);
        int kb = sub * 16 + 8 * (lane >> 5);
        bf16x8 h, l;
#pragma unroll
        for (int j = 0; j < 8; ++j) {
            float w = Wsrc[(kb + j) * 128 + col];
            bf16 hb = (bf16)w;
            bf16 lb = (bf16)(w - (float)hb);
            h[j] = hb;
            l[j] = lb;
        }
        int idx = m * 16384 + ((grp & 31) * 64 + lane) * 8;
        *(bf16x8*)&WfH[idx] = h;
        *(bf16x8*)&WfL[idx] = l;
    } else if (b < 260) {
        int i = (b - 64) * 256 + t;
        if (i < NBUCK) bucketCnt[i] = 0;
        if (i < 2048) stats[i] = 0.f;
        if (i < 32768) ppart[i] = 0.f;
        if (i < 512) plglob[i] = 0.f;
        if (i < 128) pooled4[i] = 0.f;
        if (i < 2) done[i] = 0;
    } else {
        // conv0: fp16-round h0 (pool of hidden_rep[0] happens in agg's self-term)
        int c = (t & 31) << 2;
        int rrow = t >> 5;
        for (int r = (b - 260) * 8 + rrow; r < N_NODES; r += 512 * 8) {
            float4 v = *(const float4*)&h0[r * D + c];
            f16x4 h4;
            h4[0] = (f16)v.x; h4[1] = (f16)v.y; h4[2] = (f16)v.z; h4[3] = (f16)v.w;
            *(f16x4*)&Hb[r * D + c] = h4;
        }
    }
}

// ---------------- bucket pass 1: edges -> bucket-major store (coalesced runs) ---------
// 128 blocks x 6250 edges; LDS staging; one global atomicAdd per (block,bucket).
__global__ __launch_bounds__(256)
void bucket1_kernel(const int* __restrict__ src, const int* __restrict__ dst,
                    int* __restrict__ bucketCnt, int2* __restrict__ bstore) {
    __shared__ int2 ed[6250];     // 50 KB
    __shared__ int cnt[NBUCK];
    __shared__ int offs[NBUCK];
    __shared__ int lcur[NBUCK];
    int b = blockIdx.x, t = threadIdx.x;
    int e0 = b * 6250;
    for (int i = t; i < 6250; i += 256) ed[i] = make_int2(src[e0 + i], dst[e0 + i]);
    if (t < NBUCK) { cnt[t] = 0; lcur[t] = 0; }
    __syncthreads();
    for (int i = t; i < 6250; i += 256) atomicAdd(&cnt[ed[i].y >> 9], 1);
    __syncthreads();
    if (t < NBUCK) offs[t] = atomicAdd(&bucketCnt[t], cnt[t]);
    __syncthreads();
    for (int i = t; i < 6250; i += 256) {
        int2 e = ed[i];
        int k = e.y >> 9;
        int li = atomicAdd(&lcur[k], 1);
        bstore[k * BCAP + offs[k] + li] = e;
    }
}

// ---------------- bucket pass 2: per-bucket CSC (row_start + esrc), windowed ----------
__global__ __launch_bounds__(256)
void bucket2_kernel(const int* __restrict__ bucketCnt, const int2* __restrict__ bstore,
                    int* __restrict__ row_start, int* __restrict__ esrc) {
    __shared__ int ps[256];
    __shared__ int cnt[512];
    __shared__ int cur[512];
    int k = blockIdx.x, t = threadIdx.x;
    // base = sum of bucketCnt[0..k-1]
    ps[t] = (t < NBUCK) ? bucketCnt[t] : 0;
    __syncthreads();
    for (int off = 1; off < 256; off <<= 1) {
        int a = (t >= off) ? ps[t - off] : 0;
        __syncthreads();
        ps[t] += a;
        __syncthreads();
    }
    int base = (k == 0) ? 0 : ps[k - 1];
    int n = bucketCnt[k];
    cnt[t] = 0;
    cnt[t + 256] = 0;
    __syncthreads();
    const int2* bp = &bstore[k * BCAP];
    for (int i = t; i < n; i += 256) atomicAdd(&cnt[bp[i].y & 511], 1);
    __syncthreads();
    // exclusive scan of cnt[512] via pairwise + 256-scan
    int x0 = cnt[2 * t], x1 = cnt[2 * t + 1];
    ps[t] = x0 + x1;
    __syncthreads();
    for (int off = 1; off < 256; off <<= 1) {
        int a = (t >= off) ? ps[t - off] : 0;
        __syncthreads();
        ps[t] += a;
        __syncthreads();
    }
    int ep = (t == 0) ? 0 : ps[t - 1];
    int c0 = base + ep;
    int c1 = base + ep + x0;
    cur[2 * t] = c0;
    cur[2 * t + 1] = c1;
    int g0 = (k << 9) + 2 * t;
    if (g0 < N_NODES) row_start[g0] = c0;
    if (g0 + 1 < N_NODES) row_start[g0 + 1] = c1;
    if (k == NBUCK - 1 && t == 0) row_start[N_NODES] = N_EDGES;
    __syncthreads();
    for (int i = t; i < n; i += 256) {
        int2 e = bp[i];
        int p = atomicAdd(&cur[e.y & 511], 1);
        esrc[p] = e.x;
    }
}

// ---------------- aggregation: z[v] = f(H[v]) + sum_{e->v} f(H[src]) ------------------
// H is raw fp16 (h0 or y2 of prev layer); f = relu(bn2) when APPLY, identity otherwise.
// Self-term f(H[v]) is the pool contribution of hidden_rep[layer] -> ppart.
template <bool APPLY>
__global__ __launch_bounds__(256)
void agg_kernel(const f16* __restrict__ H, const int* __restrict__ esrc,
                const int* __restrict__ row_start, const float* __restrict__ stats,
                const float* __restrict__ gam, const float* __restrict__ bet,
                f16* __restrict__ Z, float* __restrict__ ppart) {
    __shared__ float sred[4][128];
    int wv = threadIdx.x >> 6;
    int v = blockIdx.x * 4 + wv;
    int lane = threadIdx.x & 63;
    int c2 = lane << 1;
    float a0 = 1.f, b0 = 0.f, a1 = 1.f, b1 = 0.f;
    if (APPLY) {
        float m0 = stats[c2] * (1.0f / N_NODES);
        float q0 = stats[128 + c2] * (1.0f / N_NODES);
        float g0 = gam[c2] * rsqrtf(q0 - m0 * m0 + 1e-5f);
        a0 = g0; b0 = bet[c2] - m0 * g0;
        float m1 = stats[c2 + 1] * (1.0f / N_NODES);
        float q1 = stats[128 + c2 + 1] * (1.0f / N_NODES);
        float g1 = gam[c2 + 1] * rsqrtf(q1 - m1 * m1 + 1e-5f);
        a1 = g1; b1 = bet[c2 + 1] - m1 * g1;
    }
    int beg = row_start[v], end_ = row_start[v + 1];
    f16x2 sv = *(const f16x2*)&H[v * D + c2];
    float ax = (float)sv[0], ay = (float)sv[1];
    if (APPLY) {
        ax = fmaxf(fmaf(a0, ax, b0), 0.f);
        ay = fmaxf(fmaf(a1, ay, b1), 0.f);
    }
    sred[wv][c2] = ax;
    sred[wv][c2 + 1] = ay;
    int e = beg;
    for (; e + 4 <= end_; e += 4) {
        int s0 = esrc[e], s1 = esrc[e + 1], s2 = esrc[e + 2], s3 = esrc[e + 3];
        f16x2 v0 = *(const f16x2*)&H[s0 * D + c2];
        f16x2 v1 = *(const f16x2*)&H[s1 * D + c2];
        f16x2 v2 = *(const f16x2*)&H[s2 * D + c2];
        f16x2 v3 = *(const f16x2*)&H[s3 * D + c2];
        if (APPLY) {
            ax += fmaxf(fmaf(a0, (float)v0[0], b0), 0.f) + fmaxf(fmaf(a0, (float)v1[0], b0), 0.f)
                + fmaxf(fmaf(a0, (float)v2[0], b0), 0.f) + fmaxf(fmaf(a0, (float)v3[0], b0), 0.f);
            ay += fmaxf(fmaf(a1, (float)v0[1], b1), 0.f) + fmaxf(fmaf(a1, (float)v1[1], b1), 0.f)
                + fmaxf(fmaf(a1, (float)v2[1], b1), 0.f) + fmaxf(fmaf(a1, (float)v3[1], b1), 0.f);
        } else {
            ax += (float)v0[0] + (float)v1[0] + (float)v2[0] + (float)v3[0];
            ay += (float)v0[1] + (float)v1[1] + (float)v2[1] + (float)v3[1];
        }
    }
    for (; e < end_; ++e) {
        int s0 = esrc[e];
        f16x2 v0 = *(const f16x2*)&H[s0 * D + c2];
        if (APPLY) {
            ax += fmaxf(fmaf(a0, (float)v0[0], b0), 0.f);
            ay += fmaxf(fmaf(a1, (float)v0[1], b1), 0.f);
        } else {
            ax += (float)v0[0];
            ay += (float)v0[1];
        }
    }
    f16x2 zv;
    zv[0] = (f16)ax;
    zv[1] = (f16)ay;
    *(f16x2*)&Z[v * D + c2] = zv;
    __syncthreads();
    int t = threadIdx.x;
    if (t < 128) {
        float s = sred[0][t] + sred[1][t] + sred[2][t] + sred[3][t];
        atomicAdd(&ppart[(blockIdx.x & 63) * 128 + t], s);
    }
}

// ---------------- matmul: Y(f16) = f(X f16) @ W via split-bf16 MFMA (3 passes) --------
// hi/lo bf16 split represents fp16 inputs exactly; lo*lo term dropped (~2^-16 rel).
template <bool BN_IN>
__global__ __launch_bounds__(256, 2)
void mm_kernel(const f16* __restrict__ X, const bf16* __restrict__ WfH,
               const bf16* __restrict__ WfL, const float* __restrict__ stats_in,
               const float* __restrict__ gam, const float* __restrict__ bet,
               f16* __restrict__ Y, float* __restrict__ stats_out) {
    __shared__ bf16 Ah[4096];  // [128 rows][32 k], XOR-swizzled
    __shared__ bf16 Al[4096];
    __shared__ float ab[2][128];

    int t = threadIdx.x;
    int w = t >> 6, lane = t & 63;
    if (BN_IN && t < 128) {
        float s = stats_in[t] * (1.0f / N_NODES);
        float q = stats_in[128 + t] * (1.0f / N_NODES);
        float a = gam[t] * rsqrtf(q - s * s + 1e-5f);
        ab[0][t] = a;
        ab[1][t] = bet[t] - s * a;
    }

    bf16x8 Bh[8], Bl[8];
#pragma unroll
    for (int c = 0; c < 8; ++c) {
        int idx = ((w * 8 + c) * 64 + lane) * 8;
        Bh[c] = *(const bf16x8*)&WfH[idx];
        Bl[c] = *(const bf16x8*)&WfL[idx];
    }

    f32x16 acc[4];
#pragma unroll
    for (int fr = 0; fr < 4; ++fr) acc[fr] = (f32x16)0.0f;

    int rowbase = blockIdx.x * 128;
    int nrows = min(128, N_NODES - rowbase);
    int srow = t >> 1;
    int sk0 = (t & 1) * 16;
    __syncthreads();  // ab ready

    for (int kb = 0; kb < 4; ++kb) {
        if (kb) __syncthreads();
        {
            float vf[16];
#pragma unroll
            for (int j = 0; j < 16; ++j) vf[j] = 0.f;
            if (srow < nrows) {
                const f16* xr = &X[(rowbase + srow) * D + kb * 32 + sk0];
                f16x8 u0 = *(const f16x8*)&xr[0];
                f16x8 u1 = *(const f16x8*)&xr[8];
#pragma unroll
                for (int j = 0; j < 8; ++j) {
                    vf[j] = (float)u0[j];
                    vf[8 + j] = (float)u1[j];
                }
                if (BN_IN) {
#pragma unroll
                    for (int j = 0; j < 16; ++j) {
                        int kg = kb * 32 + sk0 + j;
                        vf[j] = fmaxf(fmaf(ab[0][kg], vf[j], ab[1][kg]), 0.f);
                    }
                }
            }
#pragma unroll
            for (int i = 0; i < 4; ++i) {
                bf16x4 h4, l4;
#pragma unroll
                for (int j = 0; j < 4; ++j) {
                    bf16 hb = (bf16)vf[i * 4 + j];
                    h4[j] = hb;
                    l4[j] = (bf16)(vf[i * 4 + j] - (float)hb);
                }
                int e = srow * 32 + sk0 + i * 4;
                int es = e ^ ((srow & 7) << 3);
                *(bf16x4*)&Ah[es] = h4;
                *(bf16x4*)&Al[es] = l4;
            }
        }
        __syncthreads();
#pragma unroll
        for (int s2 = 0; s2 < 2; ++s2) {
            int sg = kb * 2 + s2;
#pragma unroll
            for (int fr = 0; fr < 4; ++fr) {
                int row = fr * 32 + (lane & 31);
                int e = row * 32 + s2 * 16 + 8 * (lane >> 5);
                int es = e ^ ((row & 7) << 3);
                bf16x8 ah = *(const bf16x8*)&Ah[es];
                bf16x8 al = *(const bf16x8*)&Al[es];
                acc[fr] = __builtin_amdgcn_mfma_f32_32x32x16_bf16(al, Bh[sg], acc[fr], 0, 0, 0);
                acc[fr] = __builtin_amdgcn_mfma_f32_32x32x16_bf16(ah, Bl[sg], acc[fr], 0, 0, 0);
                acc[fr] = __builtin_amdgcn_mfma_f32_32x32x16_bf16(ah, Bh[sg], acc[fr], 0, 0, 0);
            }
        }
    }

    // C/D frag: col = lane&31, row = (reg&3) + 8*(reg>>2) + 4*(lane>>5)
    int col = w * 32 + (lane & 31);
    float psum = 0.f, psq = 0.f;
#pragma unroll
    for (int fr = 0; fr < 4; ++fr) {
#pragma unroll
        for (int r = 0; r < 16; ++r) {
            float v = acc[fr][r];
            int row = fr * 32 + (r & 3) + 8 * (r >> 2) + 4 * (lane >> 5);
            if (row < nrows) Y[(rowbase + row) * D + col] = (f16)v;
            psum += v;
            psq += v * v;
        }
    }
    psum += __shfl_xor(psum, 32);
    psq += __shfl_xor(psq, 32);
    if (lane < 32) {
        atomicAdd(&stats_out[col], psum);
        atomicAdd(&stats_out[128 + col], psq);
    }
}

// ---------------- final pool + parallel head (done-counter merge) ---------------------
__global__ __launch_bounds__(256)
void pool4head_kernel(const f16* __restrict__ Y, const float* __restrict__ stats,
                      const float* __restrict__ gam, const float* __restrict__ bet,
                      const float* __restrict__ ppart, float* __restrict__ plglob,
                      float* __restrict__ pooled4, const float* __restrict__ pW,
                      const float* __restrict__ pB, float* __restrict__ out,
                      int* __restrict__ done) {
    __shared__ float abS[2][128];
    __shared__ float red[8][128];
    __shared__ int lastflag;
    int t = threadIdx.x, b = blockIdx.x;

    // blocks 0..3: reduce ppart layer b -> plglob (pipelined, coalesced)
    if (b < 4 && t < 128) {
        float s = 0.f;
#pragma unroll
        for (int sl = 0; sl < 64; ++sl) s += ppart[b * 8192 + sl * 128 + t];
        __hip_atomic_store(&plglob[b * 128 + t], s, __ATOMIC_RELEASE,
                           __HIP_MEMORY_SCOPE_AGENT);
    }

    // all blocks: pool of relu(bn2_3(Y))
    if (t < 128) {
        float s = stats[t] * (1.0f / N_NODES);
        float q = stats[128 + t] * (1.0f / N_NODES);
        float a = gam[t] * rsqrtf(q - s * s + 1e-5f);
        abS[0][t] = a;
        abS[1][t] = bet[t] - s * a;
    }
    __syncthreads();
    int c = (t & 31) << 2;
    int rrow = t >> 5;
    float4 A = *(const float4*)&abS[0][c];
    float4 B = *(const float4*)&abS[1][c];
    float4 p = make_float4(0.f, 0.f, 0.f, 0.f);
    for (int r = b * 8 + rrow; r < N_NODES; r += gridDim.x * 8) {
        f16x4 v = *(const f16x4*)&Y[r * D + c];
        p.x += fmaxf(fmaf(A.x, (float)v[0], B.x), 0.f);
        p.y += fmaxf(fmaf(A.y, (float)v[1], B.y), 0.f);
        p.z += fmaxf(fmaf(A.z, (float)v[2], B.z), 0.f);
        p.w += fmaxf(fmaf(A.w, (float)v[3], B.w), 0.f);
    }
    *(float4*)&red[rrow][c] = p;
    __syncthreads();
    if (t < 128) {
        float s = 0.f;
#pragma unroll
        for (int i = 0; i < 8; ++i) s += red[i][t];
        atomicAdd(&pooled4[t], s);
    }
    __syncthreads();
    if (t == 0) {
        __threadfence();
        int v = atomicAdd(&done[1], 1);
        lastflag = (v == (int)gridDim.x - 1);
    }
    __syncthreads();
    if (!lastflag) return;

    // last block: parallel head GEMV (o = t&63, 4-way K split, 2 accumulators)
    __shared__ float pl[5][128];
    __shared__ float red2[4][64];
    if (t < 128) {
#pragma unroll
        for (int l = 0; l < 4; ++l)
            pl[l][t] = __hip_atomic_load(&plglob[l * 128 + t], __ATOMIC_ACQUIRE,
                                         __HIP_MEMORY_SCOPE_AGENT);
        pl[4][t] = __hip_atomic_load(&pooled4[t], __ATOMIC_ACQUIRE,
                                     __HIP_MEMORY_SCOPE_AGENT);
    }
    __syncthreads();
    int o = t & 63, q = t >> 6;
    float acc0 = 0.f, acc1 = 0.f;
#pragma unroll
    for (int l = 0; l < 5; ++l) {
        const float* wp = pW + l * 8192;
#pragma unroll
        for (int cc = 0; cc < 16; ++cc) {
            int c0 = q * 32 + cc;
            int c1 = q * 32 + 16 + cc;
            acc0 += pl[l][c0] * wp[c0 * 64 + o];
            acc1 += pl[l][c1] * wp[c1 * 64 + o];
        }
    }
    red2[q][o] = acc0 + acc1;
    __syncthreads();
    if (t < 64) {
        float s = red2[0][t] + red2[1][t] + red2[2][t] + red2[3][t];
#pragma unroll
        for (int l = 0; l < 5; ++l) s += pB[l * 64 + t];
        out[t] = s;
    }
}

extern "C" void kernel_launch(void* const* d_in, const int* in_sizes, int n_in,
                              void* d_out, int out_size, void* d_ws, size_t ws_size,
                              hipStream_t stream) {
    const float* h0 = (const float*)d_in[0];
    const int* src = (const int*)d_in[1];
    const int* dst = (const int*)d_in[2];
    const float* W1 = (const float*)d_in[3];
    const float* W2 = (const float*)d_in[4];
    const float* bn1_g = (const float*)d_in[5];
    const float* bn1_b = (const float*)d_in[6];
    const float* bn2_g = (const float*)d_in[7];
    const float* bn2_b = (const float*)d_in[8];
    const float* pW = (const float*)d_in[9];
    const float* pB = (const float*)d_in[10];
    float* out = (float*)d_out;

    char* ws = (char*)d_ws;
    f16* B0 = (f16*)(ws + 0);                   // h-carrier (hb0 / y2), 12.8 MB
    f16* B1 = (f16*)(ws + 12800000);            // z, 12.8 MB
    f16* B2 = (f16*)(ws + 25600000);            // y1, 12.8 MB
    int* esrc = (int*)(ws + 38400000);          // 3.2 MB
    int2* bstore = (int2*)(ws + 41600016);      // 98*16384*8 = 12,845,056 B
    int* bucketCnt = (int*)(ws + 54445072);     // 392 B
    int* row_start = (int*)(ws + 54445472);     // 200,004 B
    int* done = (int*)(ws + 54645504);          // 8 B
    float* stats = (float*)(ws + 54645568);     // 8 KB: [bn1 x4][bn2 x4] x 256 f
    float* ppart = (float*)(ws + 54653760);     // 4 layers x 64 x 128 = 128 KB
    float* plglob = (float*)(ws + 54784832);    // 4 x 128 f
    float* pooled4 = (float*)(ws + 54786880);   // 128 f
    bf16* WfH = (bf16*)(ws + 54787392);         // 256 KB
    bf16* WfL = (bf16*)(ws + 55049536);         // 256 KB

    initprep_kernel<<<772, 256, 0, stream>>>(W1, W2, WfH, WfL, bucketCnt, stats, ppart,
                                             plglob, pooled4, done, h0, B0);
    bucket1_kernel<<<128, 256, 0, stream>>>(src, dst, bucketCnt, bstore);
    bucket2_kernel<<<NBUCK, 256, 0, stream>>>(bucketCnt, bstore, row_start, esrc);

    for (int i = 0; i < 4; ++i) {
        if (i == 0) {
            agg_kernel<false><<<12500, 256, 0, stream>>>(B0, esrc, row_start, nullptr,
                                                         nullptr, nullptr, B1, ppart);
        } else {
            agg_kernel<true><<<12500, 256, 0, stream>>>(
                B0, esrc, row_start, stats + (4 + i - 1) * 256, bn2_g + (i - 1) * 128,
                bn2_b + (i - 1) * 128, B1, ppart + i * 8192);
        }
        mm_kernel<false><<<391, 256, 0, stream>>>(B1, WfH + i * 16384, WfL + i * 16384,
                                                  nullptr, nullptr, nullptr, B2,
                                                  stats + i * 256);
        mm_kernel<true><<<391, 256, 0, stream>>>(B2, WfH + (4 + i) * 16384,
                                                 WfL + (4 + i) * 16384, stats + i * 256,
                                                 bn1_g + i * 128, bn1_b + i * 128, B0,
                                                 stats + (4 + i) * 256);
    }
    pool4head_kernel<<<512, 256, 0, stream>>>(B0, stats + 7 * 256, bn2_g + 3 * 128,
                                              bn2_b + 3 * 128, ppart, plglob, pooled4, pW,
                                              pB, out, done);
}